// Round 1
// baseline (1431.712 us; speedup 1.0000x reference)
//
#include <hip/hip_runtime.h>

#define D 32          // feature dim (D_IN == D_OUT == 32)
#define D4 8          // float4s per row

// ---------------- degree accumulation ----------------
__global__ void deg_kernel(const int* __restrict__ dst, float* __restrict__ deg, int E) {
    int e = blockIdx.x * blockDim.x + threadIdx.x;
    if (e < E) atomicAdd(&deg[dst[e]], 1.0f);
}

// deg -> norm in place: norm = rsqrt(max(deg,1))
__global__ void norm_kernel(float* __restrict__ dn, int n) {
    int v = blockIdx.x * blockDim.x + threadIdx.x;
    if (v < n) dn[v] = rsqrtf(fmaxf(dn[v], 1.0f));
}

// ---------------- prep: A = feat*norm, g = alpha0*feat ----------------
__global__ void prep_kernel(const float4* __restrict__ feat4,
                            const float* __restrict__ norm,
                            const float* __restrict__ alpha,
                            float4* __restrict__ A4,
                            float4* __restrict__ g4, int n4) {
    int i = blockIdx.x * blockDim.x + threadIdx.x;
    if (i >= n4) return;
    int v = i >> 3;                 // D4 = 8 float4 per row
    float nv = norm[v];
    float a0 = alpha[0];
    float4 f = feat4[i];
    A4[i] = make_float4(f.x * nv, f.y * nv, f.z * nv, f.w * nv);
    g4[i] = make_float4(f.x * a0, f.y * a0, f.z * a0, f.w * a0);
}

// ---------------- scatter: B[dst] += A[src], per (edge, quad) ----------------
__global__ void scatter_kernel(const int* __restrict__ src,
                               const int* __restrict__ dst,
                               const float4* __restrict__ A4,
                               float* __restrict__ B, int total) {
    int t = blockIdx.x * blockDim.x + threadIdx.x;
    if (t >= total) return;
    int e = t >> 3;                 // edge
    int q = t & 7;                  // quad within row
    int s = src[e];
    int d = dst[e];
    float4 val = A4[s * D4 + q];
    float* bp = &B[d * D + q * 4];
    atomicAdd(bp + 0, val.x);
    atomicAdd(bp + 1, val.y);
    atomicAdd(bp + 2, val.z);
    atomicAdd(bp + 3, val.w);
}

// ---------------- post hop1: h1 = B*norm; g += a1*h1; A = B*norm^2; B = 0 ----
__global__ void post1_kernel(float4* __restrict__ B4,
                             float4* __restrict__ A4,
                             float4* __restrict__ g4,
                             const float* __restrict__ norm,
                             const float* __restrict__ alpha, int n4) {
    int i = blockIdx.x * blockDim.x + threadIdx.x;
    if (i >= n4) return;
    int v = i >> 3;
    float nv = norm[v];
    float a1 = alpha[1];
    float4 s = B4[i];
    B4[i] = make_float4(0.f, 0.f, 0.f, 0.f);          // reset accumulator for hop 2
    float4 h1 = make_float4(s.x * nv, s.y * nv, s.z * nv, s.w * nv);
    float4 g = g4[i];
    g4[i] = make_float4(fmaf(a1, h1.x, g.x), fmaf(a1, h1.y, g.y),
                        fmaf(a1, h1.z, g.z), fmaf(a1, h1.w, g.w));
    A4[i] = make_float4(h1.x * nv, h1.y * nv, h1.z * nv, h1.w * nv);  // hop-2 gather source
}

// ---------------- post hop2: g += a2 * B*norm ----------------
__global__ void post2_kernel(const float4* __restrict__ B4,
                             float4* __restrict__ g4,
                             const float* __restrict__ norm,
                             const float* __restrict__ alpha, int n4) {
    int i = blockIdx.x * blockDim.x + threadIdx.x;
    if (i >= n4) return;
    int v = i >> 3;
    float nv = norm[v];
    float a2 = alpha[2];
    float4 s = B4[i];
    float4 g = g4[i];
    g4[i] = make_float4(fmaf(a2, s.x * nv, g.x), fmaf(a2, s.y * nv, g.y),
                        fmaf(a2, s.z * nv, g.z), fmaf(a2, s.w * nv, g.w));
}

// ---------------- in-place row GEMM: out = g @ W^T + 3*b ----------------
// block = 256 threads -> 8 rows; W cached in LDS, padded to kill bank conflicts.
__global__ void gemm_kernel(float* __restrict__ g,         // in-place (d_out)
                            const float* __restrict__ W,   // [D_OUT][D_IN] row-major
                            const float* __restrict__ b,
                            int n, float bias_scale) {
    __shared__ float Wl[D][D + 1];
    __shared__ float gl[8][D];
    int tid = threadIdx.x;
    for (int k = tid; k < D * D; k += 256) Wl[k >> 5][k & 31] = W[k];
    int v0 = blockIdx.x * 8;
    int lr = tid >> 5;          // local row 0..7
    int o  = tid & 31;          // output feature
    int vload = v0 + lr;
    if (vload < n) gl[lr][o] = g[v0 * D + tid];
    __syncthreads();
    int v = v0 + lr;
    if (v < n) {
        float acc = bias_scale * b[o];
        #pragma unroll
        for (int k = 0; k < D; ++k) acc = fmaf(gl[lr][k], Wl[o][k], acc);
        g[v * D + o] = acc;
    }
}

extern "C" void kernel_launch(void* const* d_in, const int* in_sizes, int n_in,
                              void* d_out, int out_size, void* d_ws, size_t ws_size,
                              hipStream_t stream) {
    const float* feat  = (const float*)d_in[0];
    const int*   src   = (const int*)  d_in[1];
    const int*   dst   = (const int*)  d_in[2];
    const float* W     = (const float*)d_in[3];
    const float* b     = (const float*)d_in[4];
    const float* alpha = (const float*)d_in[5];

    const int N = in_sizes[0] / D;
    const int E = in_sizes[1];
    const int n4 = N * D4;          // float4 elements per feature buffer

    // workspace layout (floats): [norm: N][A: N*D][B: N*D]
    float* norm = (float*)d_ws;
    float* A    = norm + N;
    float* B    = A + (size_t)N * D;
    float* g    = (float*)d_out;    // combined features staged in d_out, GEMM'd in place

    // zero degree and hop-1 accumulator (every call: ws is not re-initialized)
    hipMemsetAsync(norm, 0, (size_t)N * sizeof(float), stream);
    hipMemsetAsync(B, 0, (size_t)N * D * sizeof(float), stream);

    const int BT = 256;
    deg_kernel<<<(E + BT - 1) / BT, BT, 0, stream>>>(dst, norm, E);
    norm_kernel<<<(N + BT - 1) / BT, BT, 0, stream>>>(norm, N);
    prep_kernel<<<(n4 + BT - 1) / BT, BT, 0, stream>>>(
        (const float4*)feat, norm, alpha, (float4*)A, (float4*)g, n4);

    const int stot = E * D4;        // E * 8 = 12.8M threads
    scatter_kernel<<<(stot + BT - 1) / BT, BT, 0, stream>>>(src, dst, (const float4*)A, B, stot);
    post1_kernel<<<(n4 + BT - 1) / BT, BT, 0, stream>>>(
        (float4*)B, (float4*)A, (float4*)g, norm, alpha, n4);

    scatter_kernel<<<(stot + BT - 1) / BT, BT, 0, stream>>>(src, dst, (const float4*)A, B, stot);
    post2_kernel<<<(n4 + BT - 1) / BT, BT, 0, stream>>>(
        (const float4*)B, (float4*)g, norm, alpha, n4);

    gemm_kernel<<<(N + 7) / 8, BT, 0, stream>>>(g, W, b, N, 3.0f /* (K+1)*b */);
}

// Round 2
// 394.602 us; speedup vs baseline: 3.6282x; 3.6282x over previous
//
#include <hip/hip_runtime.h>

#define D 32
#define D4 8
#define SCAN_T 256
#define SCAN_V 4
#define SCAN_CHUNK 1024   // SCAN_T * SCAN_V

// ---------------- degree histogram (int) ----------------
__global__ void deg_kernel(const int* __restrict__ dst, int* __restrict__ deg, int E) {
    int e = blockIdx.x * blockDim.x + threadIdx.x;
    if (e < E) atomicAdd(&deg[dst[e]], 1);
}

// ---------------- 3-kernel exclusive scan over deg ----------------
__global__ void scan1_kernel(const int* __restrict__ deg, int* __restrict__ partial, int n) {
    __shared__ int sdata[SCAN_T];
    int base = blockIdx.x * SCAN_CHUNK + threadIdx.x * SCAN_V;
    int s = 0;
    #pragma unroll
    for (int k = 0; k < SCAN_V; ++k) { int i = base + k; if (i < n) s += deg[i]; }
    sdata[threadIdx.x] = s;
    __syncthreads();
    for (int off = SCAN_T / 2; off > 0; off >>= 1) {
        if (threadIdx.x < off) sdata[threadIdx.x] += sdata[threadIdx.x + off];
        __syncthreads();
    }
    if (threadIdx.x == 0) partial[blockIdx.x] = sdata[0];
}

__global__ void scan2_kernel(int* __restrict__ partial, int nb) {
    __shared__ int sdata[256];
    int v = (threadIdx.x < nb) ? partial[threadIdx.x] : 0;
    sdata[threadIdx.x] = v;
    __syncthreads();
    for (int off = 1; off < 256; off <<= 1) {
        int t = (threadIdx.x >= off) ? sdata[threadIdx.x - off] : 0;
        __syncthreads();
        sdata[threadIdx.x] += t;
        __syncthreads();
    }
    if (threadIdx.x < nb) partial[threadIdx.x] = sdata[threadIdx.x] - v;  // exclusive
}

// writes row_start, next (=row_start copy), and norm = rsqrt(max(deg,1))
__global__ void scan3_kernel(const int* __restrict__ deg, const int* __restrict__ partial,
                             int* __restrict__ row_start, int* __restrict__ next,
                             float* __restrict__ norm, int n) {
    __shared__ int sdata[SCAN_T];
    int base = blockIdx.x * SCAN_CHUNK + threadIdx.x * SCAN_V;
    int v[SCAN_V];
    int s = 0;
    #pragma unroll
    for (int k = 0; k < SCAN_V; ++k) { int i = base + k; v[k] = (i < n) ? deg[i] : 0; s += v[k]; }
    int self = s;
    sdata[threadIdx.x] = s;
    __syncthreads();
    for (int off = 1; off < SCAN_T; off <<= 1) {
        int t = (threadIdx.x >= off) ? sdata[threadIdx.x - off] : 0;
        __syncthreads();
        sdata[threadIdx.x] += t;
        __syncthreads();
    }
    int run = partial[blockIdx.x] + sdata[threadIdx.x] - self;
    #pragma unroll
    for (int k = 0; k < SCAN_V; ++k) {
        int i = base + k;
        if (i < n) {
            row_start[i] = run;
            next[i] = run;
            norm[i] = rsqrtf(fmaxf((float)v[k], 1.0f));
            run += v[k];
        }
    }
}

// ---------------- CSR fill: csr_src[pos] = src[e], pos = next[dst]++ ----------------
__global__ void fill_kernel(const int* __restrict__ src, const int* __restrict__ dst,
                            int* __restrict__ next, int* __restrict__ csr_src, int E) {
    int e = blockIdx.x * blockDim.x + threadIdx.x;
    if (e < E) {
        int pos = atomicAdd(&next[dst[e]], 1);
        csr_src[pos] = src[e];
    }
}

// ---------------- prep: A = feat*norm, g = alpha0*feat ----------------
__global__ void prep_kernel(const float4* __restrict__ feat4,
                            const float* __restrict__ norm,
                            const float* __restrict__ alpha,
                            float4* __restrict__ A4,
                            float4* __restrict__ g4, int n4) {
    int i = blockIdx.x * blockDim.x + threadIdx.x;
    if (i >= n4) return;
    int v = i >> 3;
    float nv = norm[v];
    float a0 = alpha[0];
    float4 f = feat4[i];
    A4[i] = make_float4(f.x * nv, f.y * nv, f.z * nv, f.w * nv);
    g4[i] = make_float4(f.x * a0, f.y * a0, f.z * a0, f.w * a0);
}

// ---------------- pull SpMM: B[d] = sum_{e in row d} A[csr_src[e]] ----------------
// one wave (64 lanes) per dst row: 32 lanes = features, 2 edges per iteration
__global__ void gather_kernel(const int* __restrict__ row_start,
                              const int* __restrict__ row_end,
                              const int* __restrict__ csr_src,
                              const float* __restrict__ A,
                              float* __restrict__ B, int n) {
    int w = blockIdx.x * (blockDim.x >> 6) + (threadIdx.x >> 6);
    if (w >= n) return;
    int lane = threadIdx.x & 63;
    int half = lane >> 5;
    int c = lane & 31;
    int s0 = row_start[w];
    int e1 = row_end[w];
    float acc = 0.f;
    for (int j = s0 + half; j < e1; j += 2) {
        int s = csr_src[j];
        acc += A[(size_t)s * D + c];
    }
    acc += __shfl_xor(acc, 32);
    if (half == 0) B[(size_t)w * D + c] = acc;
}

// ---------------- post hop1: h1 = B*norm; g += a1*h1; A = h1*norm ----------------
__global__ void post1_kernel(const float4* __restrict__ B4,
                             float4* __restrict__ A4,
                             float4* __restrict__ g4,
                             const float* __restrict__ norm,
                             const float* __restrict__ alpha, int n4) {
    int i = blockIdx.x * blockDim.x + threadIdx.x;
    if (i >= n4) return;
    int v = i >> 3;
    float nv = norm[v];
    float a1 = alpha[1];
    float4 s = B4[i];
    float4 h1 = make_float4(s.x * nv, s.y * nv, s.z * nv, s.w * nv);
    float4 g = g4[i];
    g4[i] = make_float4(fmaf(a1, h1.x, g.x), fmaf(a1, h1.y, g.y),
                        fmaf(a1, h1.z, g.z), fmaf(a1, h1.w, g.w));
    A4[i] = make_float4(h1.x * nv, h1.y * nv, h1.z * nv, h1.w * nv);
}

// ---------------- fused post2 + row GEMM: out = (g + a2*B*norm) @ W^T + 3b ----------
__global__ void gemm_kernel(float* __restrict__ g,
                            const float* __restrict__ B,
                            const float* __restrict__ norm,
                            const float* __restrict__ W,
                            const float* __restrict__ b,
                            const float* __restrict__ alpha, int n) {
    __shared__ float Wl[D][D + 1];
    __shared__ float gl[8][D];
    int tid = threadIdx.x;
    for (int k = tid; k < D * D; k += 256) Wl[k >> 5][k & 31] = W[k];
    int v0 = blockIdx.x * 8;
    int lr = tid >> 5;
    int o  = tid & 31;
    int v = v0 + lr;
    float a2 = alpha[2];
    if (v < n) {
        float nv = norm[v];
        gl[lr][o] = g[(size_t)v * D + o] + a2 * nv * B[(size_t)v * D + o];
    }
    __syncthreads();
    if (v < n) {
        float acc = 3.0f * b[o];
        #pragma unroll
        for (int k = 0; k < D; ++k) acc = fmaf(gl[lr][k], Wl[o][k], acc);
        g[(size_t)v * D + o] = acc;
    }
}

// ---------------- fallback (atomic scatter) kernels, only if ws too small ----------
__global__ void degf_kernel(const int* __restrict__ dst, float* __restrict__ deg, int E) {
    int e = blockIdx.x * blockDim.x + threadIdx.x;
    if (e < E) atomicAdd(&deg[dst[e]], 1.0f);
}
__global__ void normf_kernel(float* __restrict__ dn, int n) {
    int v = blockIdx.x * blockDim.x + threadIdx.x;
    if (v < n) dn[v] = rsqrtf(fmaxf(dn[v], 1.0f));
}
__global__ void scatter_kernel(const int* __restrict__ src, const int* __restrict__ dst,
                               const float4* __restrict__ A4, float* __restrict__ B, int total) {
    int t = blockIdx.x * blockDim.x + threadIdx.x;
    if (t >= total) return;
    int e = t >> 3, q = t & 7;
    float4 val = A4[src[e] * D4 + q];
    float* bp = &B[dst[e] * D + q * 4];
    atomicAdd(bp + 0, val.x); atomicAdd(bp + 1, val.y);
    atomicAdd(bp + 2, val.z); atomicAdd(bp + 3, val.w);
}
__global__ void post1f_kernel(float4* __restrict__ B4, float4* __restrict__ A4,
                              float4* __restrict__ g4, const float* __restrict__ norm,
                              const float* __restrict__ alpha, int n4) {
    int i = blockIdx.x * blockDim.x + threadIdx.x;
    if (i >= n4) return;
    int v = i >> 3;
    float nv = norm[v], a1 = alpha[1];
    float4 s = B4[i];
    B4[i] = make_float4(0.f, 0.f, 0.f, 0.f);
    float4 h1 = make_float4(s.x * nv, s.y * nv, s.z * nv, s.w * nv);
    float4 g = g4[i];
    g4[i] = make_float4(fmaf(a1, h1.x, g.x), fmaf(a1, h1.y, g.y),
                        fmaf(a1, h1.z, g.z), fmaf(a1, h1.w, g.w));
    A4[i] = make_float4(h1.x * nv, h1.y * nv, h1.z * nv, h1.w * nv);
}

extern "C" void kernel_launch(void* const* d_in, const int* in_sizes, int n_in,
                              void* d_out, int out_size, void* d_ws, size_t ws_size,
                              hipStream_t stream) {
    const float* feat  = (const float*)d_in[0];
    const int*   src   = (const int*)  d_in[1];
    const int*   dst   = (const int*)  d_in[2];
    const float* W     = (const float*)d_in[3];
    const float* b     = (const float*)d_in[4];
    const float* alpha = (const float*)d_in[5];

    const int N  = in_sizes[0] / D;
    const int E  = in_sizes[1];
    const int n4 = N * D4;
    const int BT = 256;
    const int nb = (N + SCAN_CHUNK - 1) / SCAN_CHUNK;   // scan blocks (<=256 required)

    size_t need = (size_t)(3 * N + 256 + E) * 4 + (size_t)(N + 2 * N * D) * 4;

    if (ws_size >= need && nb <= 256) {
        // ---- CSR pull path ----
        // ws layout: deg[N] | partial[256] | row_start[N] | next[N] | csr_src[E] | norm[N] | A[N*D] | B[N*D]
        int*   deg       = (int*)d_ws;
        int*   partial   = deg + N;
        int*   row_start = partial + 256;
        int*   next      = row_start + N;
        int*   csr_src   = next + N;
        float* norm      = (float*)(csr_src + E);
        float* A         = norm + N;
        float* B         = A + (size_t)N * D;
        float* g         = (float*)d_out;

        hipMemsetAsync(deg, 0, (size_t)N * sizeof(int), stream);
        deg_kernel<<<(E + BT - 1) / BT, BT, 0, stream>>>(dst, deg, E);
        scan1_kernel<<<nb, SCAN_T, 0, stream>>>(deg, partial, N);
        scan2_kernel<<<1, 256, 0, stream>>>(partial, nb);
        scan3_kernel<<<nb, SCAN_T, 0, stream>>>(deg, partial, row_start, next, norm, N);
        fill_kernel<<<(E + BT - 1) / BT, BT, 0, stream>>>(src, dst, next, csr_src, E);
        prep_kernel<<<(n4 + BT - 1) / BT, BT, 0, stream>>>(
            (const float4*)feat, norm, alpha, (float4*)A, (float4*)g, n4);

        const int waves_per_block = BT / 64;  // 4 rows per block
        const int gblocks = (N + waves_per_block - 1) / waves_per_block;
        gather_kernel<<<gblocks, BT, 0, stream>>>(row_start, next, csr_src, A, B, N);
        post1_kernel<<<(n4 + BT - 1) / BT, BT, 0, stream>>>(
            (const float4*)B, (float4*)A, (float4*)g, norm, alpha, n4);
        gather_kernel<<<gblocks, BT, 0, stream>>>(row_start, next, csr_src, A, B, N);
        gemm_kernel<<<(N + 7) / 8, BT, 0, stream>>>(g, B, norm, W, b, alpha, N);
    } else {
        // ---- fallback: atomic scatter path (R0 behavior) ----
        float* norm = (float*)d_ws;
        float* A    = norm + N;
        float* B    = A + (size_t)N * D;
        float* g    = (float*)d_out;
        hipMemsetAsync(norm, 0, (size_t)N * sizeof(float), stream);
        hipMemsetAsync(B, 0, (size_t)N * D * sizeof(float), stream);
        degf_kernel<<<(E + BT - 1) / BT, BT, 0, stream>>>(dst, norm, E);
        normf_kernel<<<(N + BT - 1) / BT, BT, 0, stream>>>(norm, N);
        prep_kernel<<<(n4 + BT - 1) / BT, BT, 0, stream>>>(
            (const float4*)feat, norm, alpha, (float4*)A, (float4*)g, n4);
        const int stot = E * D4;
        scatter_kernel<<<(stot + BT - 1) / BT, BT, 0, stream>>>(src, dst, (const float4*)A, B, stot);
        post1f_kernel<<<(n4 + BT - 1) / BT, BT, 0, stream>>>(
            (float4*)B, (float4*)A, (float4*)g, norm, alpha, n4);
        scatter_kernel<<<(stot + BT - 1) / BT, BT, 0, stream>>>(src, dst, (const float4*)A, B, stot);
        gemm_kernel<<<(N + 7) / 8, BT, 0, stream>>>(g, B, norm, W, b, alpha, N);
    }
}

// Round 3
// 251.182 us; speedup vs baseline: 5.6999x; 1.5710x over previous
//
#include <hip/hip_runtime.h>

#define D 32
#define D4 8
#define SCAN_T 256
#define SCAN_V 4
#define SCAN_CHUNK 1024   // SCAN_T * SCAN_V

// ---------------- degree histogram + per-edge slot (path A) ----------------
__global__ void degpos_kernel(const int* __restrict__ dst, int* __restrict__ deg,
                              int* __restrict__ pos, int E) {
    int e = blockIdx.x * blockDim.x + threadIdx.x;
    if (e < E) pos[e] = atomicAdd(&deg[dst[e]], 1);
}

// ---------------- degree histogram only (path B) ----------------
__global__ void deg_kernel(const int* __restrict__ dst, int* __restrict__ deg, int E) {
    int e = blockIdx.x * blockDim.x + threadIdx.x;
    if (e < E) atomicAdd(&deg[dst[e]], 1);
}

// ---------------- 3-kernel exclusive scan over deg ----------------
__global__ void scan1_kernel(const int* __restrict__ deg, int* __restrict__ partial, int n) {
    __shared__ int sdata[SCAN_T];
    int base = blockIdx.x * SCAN_CHUNK + threadIdx.x * SCAN_V;
    int s = 0;
    #pragma unroll
    for (int k = 0; k < SCAN_V; ++k) { int i = base + k; if (i < n) s += deg[i]; }
    sdata[threadIdx.x] = s;
    __syncthreads();
    for (int off = SCAN_T / 2; off > 0; off >>= 1) {
        if (threadIdx.x < off) sdata[threadIdx.x] += sdata[threadIdx.x + off];
        __syncthreads();
    }
    if (threadIdx.x == 0) partial[blockIdx.x] = sdata[0];
}

__global__ void scan2_kernel(int* __restrict__ partial, int nb) {
    __shared__ int sdata[256];
    int v = (threadIdx.x < nb) ? partial[threadIdx.x] : 0;
    sdata[threadIdx.x] = v;
    __syncthreads();
    for (int off = 1; off < 256; off <<= 1) {
        int t = (threadIdx.x >= off) ? sdata[threadIdx.x - off] : 0;
        __syncthreads();
        sdata[threadIdx.x] += t;
        __syncthreads();
    }
    if (threadIdx.x < nb) partial[threadIdx.x] = sdata[threadIdx.x] - v;  // exclusive
}

// writes row_start, row_end, norm = rsqrt(max(deg,1)); optionally next(=row_start)
__global__ void scan3_kernel(const int* __restrict__ deg, const int* __restrict__ partial,
                             int* __restrict__ row_start, int* __restrict__ row_end,
                             int* __restrict__ next, float* __restrict__ norm, int n) {
    __shared__ int sdata[SCAN_T];
    int base = blockIdx.x * SCAN_CHUNK + threadIdx.x * SCAN_V;
    int v[SCAN_V];
    int s = 0;
    #pragma unroll
    for (int k = 0; k < SCAN_V; ++k) { int i = base + k; v[k] = (i < n) ? deg[i] : 0; s += v[k]; }
    int self = s;
    sdata[threadIdx.x] = s;
    __syncthreads();
    for (int off = 1; off < SCAN_T; off <<= 1) {
        int t = (threadIdx.x >= off) ? sdata[threadIdx.x - off] : 0;
        __syncthreads();
        sdata[threadIdx.x] += t;
        __syncthreads();
    }
    int run = partial[blockIdx.x] + sdata[threadIdx.x] - self;
    #pragma unroll
    for (int k = 0; k < SCAN_V; ++k) {
        int i = base + k;
        if (i < n) {
            row_start[i] = run;
            row_end[i]   = run + v[k];
            if (next) next[i] = run;
            norm[i] = rsqrtf(fmaxf((float)v[k], 1.0f));
            run += v[k];
        }
    }
}

// ---------------- CSR fill, atomic-free (path A) ----------------
__global__ void fillA_kernel(const int* __restrict__ src, const int* __restrict__ dst,
                             const int* __restrict__ pos, const int* __restrict__ row_start,
                             int* __restrict__ csr_src, int E) {
    int e = blockIdx.x * blockDim.x + threadIdx.x;
    if (e < E) csr_src[row_start[dst[e]] + pos[e]] = src[e];
}

// ---------------- CSR fill with atomic cursor (path B) ----------------
__global__ void fillB_kernel(const int* __restrict__ src, const int* __restrict__ dst,
                             int* __restrict__ next, int* __restrict__ csr_src, int E) {
    int e = blockIdx.x * blockDim.x + threadIdx.x;
    if (e < E) {
        int p = atomicAdd(&next[dst[e]], 1);
        csr_src[p] = src[e];
    }
}

// ---------------- prep: A = feat*norm, g = alpha0*feat ----------------
__global__ void prep_kernel(const float4* __restrict__ feat4,
                            const float* __restrict__ norm,
                            const float* __restrict__ alpha,
                            float4* __restrict__ A4,
                            float4* __restrict__ g4, int n4) {
    int i = blockIdx.x * blockDim.x + threadIdx.x;
    if (i >= n4) return;
    int v = i >> 3;
    float nv = norm[v];
    float a0 = alpha[0];
    float4 f = feat4[i];
    A4[i] = make_float4(f.x * nv, f.y * nv, f.z * nv, f.w * nv);
    g4[i] = make_float4(f.x * a0, f.y * a0, f.z * a0, f.w * a0);
}

// ---------------- hop1 gather, fused post1: one wave per row ----------------
// acc = sum_{e in row} A[src]; h1 = acc*nv; g += a1*h1; A2 = h1*nv
__global__ void gather1_kernel(const int* __restrict__ row_start,
                               const int* __restrict__ row_end,
                               const int* __restrict__ csr_src,
                               const float* __restrict__ A,
                               const float* __restrict__ norm,
                               const float* __restrict__ alpha,
                               float* __restrict__ g,
                               float* __restrict__ A2, int n) {
    int w = blockIdx.x * (blockDim.x >> 6) + (threadIdx.x >> 6);
    if (w >= n) return;
    int lane = threadIdx.x & 63;
    int half = lane >> 5;
    int c = lane & 31;
    int s0 = row_start[w];
    int e1 = row_end[w];
    float acc = 0.f;
    int j = s0 + half;
    for (; j + 2 < e1; j += 4) {
        int sa = csr_src[j];
        int sb = csr_src[j + 2];
        acc += A[(size_t)sa * D + c];
        acc += A[(size_t)sb * D + c];
    }
    if (j < e1) acc += A[(size_t)csr_src[j] * D + c];
    acc += __shfl_xor(acc, 32);
    if (half == 0) {
        float nv = norm[w];
        float a1 = alpha[1];
        float h1 = acc * nv;
        size_t o = (size_t)w * D + c;
        g[o] = fmaf(a1, h1, g[o]);
        A2[o] = h1 * nv;
    }
}

// ---------------- hop2 gather, fused post2: g += a2 * acc * nv ----------------
__global__ void gather2_kernel(const int* __restrict__ row_start,
                               const int* __restrict__ row_end,
                               const int* __restrict__ csr_src,
                               const float* __restrict__ A2,
                               const float* __restrict__ norm,
                               const float* __restrict__ alpha,
                               float* __restrict__ g, int n) {
    int w = blockIdx.x * (blockDim.x >> 6) + (threadIdx.x >> 6);
    if (w >= n) return;
    int lane = threadIdx.x & 63;
    int half = lane >> 5;
    int c = lane & 31;
    int s0 = row_start[w];
    int e1 = row_end[w];
    float acc = 0.f;
    int j = s0 + half;
    for (; j + 2 < e1; j += 4) {
        int sa = csr_src[j];
        int sb = csr_src[j + 2];
        acc += A2[(size_t)sa * D + c];
        acc += A2[(size_t)sb * D + c];
    }
    if (j < e1) acc += A2[(size_t)csr_src[j] * D + c];
    acc += __shfl_xor(acc, 32);
    if (half == 0) {
        float nv = norm[w];
        float a2 = alpha[2];
        size_t o = (size_t)w * D + c;
        g[o] = fmaf(a2, acc * nv, g[o]);
    }
}

// ---------------- in-place row GEMM: out = g @ W^T + 3b ----------------
__global__ void gemm_kernel(float* __restrict__ g,
                            const float* __restrict__ W,
                            const float* __restrict__ b, int n) {
    __shared__ float Wl[D][D + 1];
    __shared__ float gl[8][D];
    int tid = threadIdx.x;
    for (int k = tid; k < D * D; k += 256) Wl[k >> 5][k & 31] = W[k];
    int v0 = blockIdx.x * 8;
    int lr = tid >> 5;
    int o  = tid & 31;
    int v = v0 + lr;
    if (v < n) gl[lr][o] = g[(size_t)v * D + o];
    __syncthreads();
    if (v < n) {
        float acc = 3.0f * b[o];
        #pragma unroll
        for (int k = 0; k < D; ++k) acc = fmaf(gl[lr][k], Wl[o][k], acc);
        g[(size_t)v * D + o] = acc;
    }
}

extern "C" void kernel_launch(void* const* d_in, const int* in_sizes, int n_in,
                              void* d_out, int out_size, void* d_ws, size_t ws_size,
                              hipStream_t stream) {
    const float* feat  = (const float*)d_in[0];
    const int*   src   = (const int*)  d_in[1];
    const int*   dst   = (const int*)  d_in[2];
    const float* W     = (const float*)d_in[3];
    const float* b     = (const float*)d_in[4];
    const float* alpha = (const float*)d_in[5];

    const int N  = in_sizes[0] / D;
    const int E  = in_sizes[1];
    const int n4 = N * D4;
    const int BT = 256;
    const int nb = (N + SCAN_CHUNK - 1) / SCAN_CHUNK;   // must be <= 256

    // Path A: deg[N] pos[E] partial[256] row_start[N] row_end[N] csr_src[E] norm[N] A[N*D] A2[N*D]
    size_t needA = (size_t)(4 * N + 2 * E + 256 + 2 * N * D) * 4;
    // Path B: deg[N] partial[256] row_start[N] row_end[N] next[N] csr_src[E] norm[N] A[N*D] A2[N*D]
    size_t needB = (size_t)(5 * N + E + 256 + 2 * N * D) * 4;

    const int waves_per_block = BT / 64;
    const int gblocks = (N + waves_per_block - 1) / waves_per_block;
    const int gemm_blocks = (N + 7) / 8;
    float* g = (float*)d_out;

    if (ws_size >= needA && nb <= 256) {
        int*   deg       = (int*)d_ws;
        int*   pos       = deg + N;
        int*   partial   = pos + E;
        int*   row_start = partial + 256;
        int*   row_end   = row_start + N;
        int*   csr_src   = row_end + N;
        float* norm      = (float*)(csr_src + E);
        float* A         = norm + N;
        float* A2        = A + (size_t)N * D;

        hipMemsetAsync(deg, 0, (size_t)N * sizeof(int), stream);
        degpos_kernel<<<(E + BT - 1) / BT, BT, 0, stream>>>(dst, deg, pos, E);
        scan1_kernel<<<nb, SCAN_T, 0, stream>>>(deg, partial, N);
        scan2_kernel<<<1, 256, 0, stream>>>(partial, nb);
        scan3_kernel<<<nb, SCAN_T, 0, stream>>>(deg, partial, row_start, row_end,
                                                (int*)nullptr, norm, N);
        fillA_kernel<<<(E + BT - 1) / BT, BT, 0, stream>>>(src, dst, pos, row_start, csr_src, E);
        prep_kernel<<<(n4 + BT - 1) / BT, BT, 0, stream>>>(
            (const float4*)feat, norm, alpha, (float4*)A, (float4*)g, n4);
        gather1_kernel<<<gblocks, BT, 0, stream>>>(row_start, row_end, csr_src, A, norm, alpha, g, A2, N);
        gather2_kernel<<<gblocks, BT, 0, stream>>>(row_start, row_end, csr_src, A2, norm, alpha, g, N);
        gemm_kernel<<<gemm_blocks, BT, 0, stream>>>(g, W, b, N);
    } else {
        int*   deg       = (int*)d_ws;
        int*   partial   = deg + N;
        int*   row_start = partial + 256;
        int*   row_end   = row_start + N;
        int*   next      = row_end + N;
        int*   csr_src   = next + N;
        float* norm      = (float*)(csr_src + E);
        float* A         = norm + N;
        float* A2        = A + (size_t)N * D;
        (void)needB;

        hipMemsetAsync(deg, 0, (size_t)N * sizeof(int), stream);
        deg_kernel<<<(E + BT - 1) / BT, BT, 0, stream>>>(dst, deg, E);
        scan1_kernel<<<nb, SCAN_T, 0, stream>>>(deg, partial, N);
        scan2_kernel<<<1, 256, 0, stream>>>(partial, nb);
        scan3_kernel<<<nb, SCAN_T, 0, stream>>>(deg, partial, row_start, row_end, next, norm, N);
        fillB_kernel<<<(E + BT - 1) / BT, BT, 0, stream>>>(src, dst, next, csr_src, E);
        prep_kernel<<<(n4 + BT - 1) / BT, BT, 0, stream>>>(
            (const float4*)feat, norm, alpha, (float4*)A, (float4*)g, n4);
        gather1_kernel<<<gblocks, BT, 0, stream>>>(row_start, row_end, csr_src, A, norm, alpha, g, A2, N);
        gather2_kernel<<<gblocks, BT, 0, stream>>>(row_start, row_end, csr_src, A2, norm, alpha, g, N);
        gemm_kernel<<<gemm_blocks, BT, 0, stream>>>(g, W, b, N);
    }
}

// Round 4
// 209.373 us; speedup vs baseline: 6.8381x; 1.1997x over previous
//
#include <hip/hip_runtime.h>

#define D 32
#define SCAN_T 256
#define SCAN_V 4
#define SCAN_CHUNK 1024   // SCAN_T * SCAN_V

// ---------------- degree histogram + per-edge slot, 4 edges/thread ----------------
__global__ void degpos_kernel(const int* __restrict__ dst, int* __restrict__ deg,
                              int* __restrict__ pos, int E) {
    int t = blockIdx.x * blockDim.x + threadIdx.x;
    int base = t * 4;
    if (base + 3 < E) {
        int4 d = *(const int4*)(dst + base);
        int4 p;
        p.x = atomicAdd(&deg[d.x], 1);
        p.y = atomicAdd(&deg[d.y], 1);
        p.z = atomicAdd(&deg[d.z], 1);
        p.w = atomicAdd(&deg[d.w], 1);
        *(int4*)(pos + base) = p;
    } else if (base < E) {
        for (int e = base; e < E; ++e) pos[e] = atomicAdd(&deg[dst[e]], 1);
    }
}

// ---------------- degree histogram only (fallback path) ----------------
__global__ void deg_kernel(const int* __restrict__ dst, int* __restrict__ deg, int E) {
    int t = blockIdx.x * blockDim.x + threadIdx.x;
    int base = t * 4;
    if (base + 3 < E) {
        int4 d = *(const int4*)(dst + base);
        atomicAdd(&deg[d.x], 1);
        atomicAdd(&deg[d.y], 1);
        atomicAdd(&deg[d.z], 1);
        atomicAdd(&deg[d.w], 1);
    } else if (base < E) {
        for (int e = base; e < E; ++e) atomicAdd(&deg[dst[e]], 1);
    }
}

// ---------------- 3-kernel exclusive scan over deg ----------------
__global__ void scan1_kernel(const int* __restrict__ deg, int* __restrict__ partial, int n) {
    __shared__ int sdata[SCAN_T];
    int base = blockIdx.x * SCAN_CHUNK + threadIdx.x * SCAN_V;
    int s = 0;
    #pragma unroll
    for (int k = 0; k < SCAN_V; ++k) { int i = base + k; if (i < n) s += deg[i]; }
    sdata[threadIdx.x] = s;
    __syncthreads();
    for (int off = SCAN_T / 2; off > 0; off >>= 1) {
        if (threadIdx.x < off) sdata[threadIdx.x] += sdata[threadIdx.x + off];
        __syncthreads();
    }
    if (threadIdx.x == 0) partial[blockIdx.x] = sdata[0];
}

__global__ void scan2_kernel(int* __restrict__ partial, int nb) {
    __shared__ int sdata[256];
    int v = (threadIdx.x < nb) ? partial[threadIdx.x] : 0;
    sdata[threadIdx.x] = v;
    __syncthreads();
    for (int off = 1; off < 256; off <<= 1) {
        int t = (threadIdx.x >= off) ? sdata[threadIdx.x - off] : 0;
        __syncthreads();
        sdata[threadIdx.x] += t;
        __syncthreads();
    }
    if (threadIdx.x < nb) partial[threadIdx.x] = sdata[threadIdx.x] - v;  // exclusive
}

__global__ void scan3_kernel(const int* __restrict__ deg, const int* __restrict__ partial,
                             int* __restrict__ row_start, int* __restrict__ row_end,
                             int* __restrict__ next, float* __restrict__ norm, int n) {
    __shared__ int sdata[SCAN_T];
    int base = blockIdx.x * SCAN_CHUNK + threadIdx.x * SCAN_V;
    int v[SCAN_V];
    int s = 0;
    #pragma unroll
    for (int k = 0; k < SCAN_V; ++k) { int i = base + k; v[k] = (i < n) ? deg[i] : 0; s += v[k]; }
    int self = s;
    sdata[threadIdx.x] = s;
    __syncthreads();
    for (int off = 1; off < SCAN_T; off <<= 1) {
        int t = (threadIdx.x >= off) ? sdata[threadIdx.x - off] : 0;
        __syncthreads();
        sdata[threadIdx.x] += t;
        __syncthreads();
    }
    int run = partial[blockIdx.x] + sdata[threadIdx.x] - self;
    #pragma unroll
    for (int k = 0; k < SCAN_V; ++k) {
        int i = base + k;
        if (i < n) {
            row_start[i] = run;
            row_end[i]   = run + v[k];
            if (next) next[i] = run;
            norm[i] = rsqrtf(fmaxf((float)v[k], 1.0f));
            run += v[k];
        }
    }
}

// ---------------- CSR fill, atomic-free, 4 edges/thread ----------------
__global__ void fillA_kernel(const int* __restrict__ src, const int* __restrict__ dst,
                             const int* __restrict__ pos, const int* __restrict__ row_start,
                             int* __restrict__ csr_src, int E) {
    int t = blockIdx.x * blockDim.x + threadIdx.x;
    int base = t * 4;
    if (base + 3 < E) {
        int4 d = *(const int4*)(dst + base);
        int4 p = *(const int4*)(pos + base);
        int4 s = *(const int4*)(src + base);
        int rx = row_start[d.x];
        int ry = row_start[d.y];
        int rz = row_start[d.z];
        int rw = row_start[d.w];
        csr_src[rx + p.x] = s.x;
        csr_src[ry + p.y] = s.y;
        csr_src[rz + p.z] = s.z;
        csr_src[rw + p.w] = s.w;
    } else if (base < E) {
        for (int e = base; e < E; ++e)
            csr_src[row_start[dst[e]] + pos[e]] = src[e];
    }
}

// ---------------- CSR fill with atomic cursor (fallback) ----------------
__global__ void fillB_kernel(const int* __restrict__ src, const int* __restrict__ dst,
                             int* __restrict__ next, int* __restrict__ csr_src, int E) {
    int e = blockIdx.x * blockDim.x + threadIdx.x;
    if (e < E) {
        int p = atomicAdd(&next[dst[e]], 1);
        csr_src[p] = src[e];
    }
}

__device__ __forceinline__ float4 f4_shfl_xor_add(float4 a, int mask) {
    a.x += __shfl_xor(a.x, mask);
    a.y += __shfl_xor(a.y, mask);
    a.z += __shfl_xor(a.z, mask);
    a.w += __shfl_xor(a.w, mask);
    return a;
}

// ---------------- hop1 gather (fused prep + post1) ----------------
// one wave per dst row; lane = (edge-octet eo=lane>>3, quad q=lane&7)
// acc(q) = sum_{e in row} feat4[src*8+q] * norm[src]
// h1 = acc*nv;  G1 = a0*feat[w] + a1*h1;  A2 = h1*nv
__global__ void gather1_kernel(const int* __restrict__ row_start,
                               const int* __restrict__ row_end,
                               const int* __restrict__ csr_src,
                               const float4* __restrict__ feat4,
                               const float* __restrict__ norm,
                               const float* __restrict__ alpha,
                               float4* __restrict__ G1,
                               float4* __restrict__ A2, int n) {
    int w = blockIdx.x * (blockDim.x >> 6) + (threadIdx.x >> 6);
    if (w >= n) return;
    int lane = threadIdx.x & 63;
    int eo = lane >> 3;
    int q  = lane & 7;
    int s0 = row_start[w];
    int e1 = row_end[w];
    float4 acc = make_float4(0.f, 0.f, 0.f, 0.f);
    int j = s0 + eo;
    for (; j + 8 < e1; j += 16) {
        int sa = csr_src[j];
        int sb = csr_src[j + 8];
        float na = norm[sa];
        float nb = norm[sb];
        float4 va = feat4[(size_t)sa * 8 + q];
        float4 vb = feat4[(size_t)sb * 8 + q];
        acc.x += va.x * na + vb.x * nb;
        acc.y += va.y * na + vb.y * nb;
        acc.z += va.z * na + vb.z * nb;
        acc.w += va.w * na + vb.w * nb;
    }
    if (j < e1) {
        int sa = csr_src[j];
        float na = norm[sa];
        float4 va = feat4[(size_t)sa * 8 + q];
        acc.x += va.x * na; acc.y += va.y * na;
        acc.z += va.z * na; acc.w += va.w * na;
    }
    acc = f4_shfl_xor_add(acc, 8);
    acc = f4_shfl_xor_add(acc, 16);
    acc = f4_shfl_xor_add(acc, 32);
    if (lane < 8) {
        float nv = norm[w];
        float a0 = alpha[0], a1 = alpha[1];
        float4 f = feat4[(size_t)w * 8 + q];
        float4 h1 = make_float4(acc.x * nv, acc.y * nv, acc.z * nv, acc.w * nv);
        size_t o = (size_t)w * 8 + q;
        G1[o] = make_float4(fmaf(a1, h1.x, a0 * f.x), fmaf(a1, h1.y, a0 * f.y),
                            fmaf(a1, h1.z, a0 * f.z), fmaf(a1, h1.w, a0 * f.w));
        A2[o] = make_float4(h1.x * nv, h1.y * nv, h1.z * nv, h1.w * nv);
    }
}

// ---------------- hop2 gather (fused post2 + GEMM) ----------------
// acc(q) = sum A2[src]; p = G1[w] + a2*acc*nv; out[w] = p @ W^T + 3b
__global__ void gather2_kernel(const int* __restrict__ row_start,
                               const int* __restrict__ row_end,
                               const int* __restrict__ csr_src,
                               const float4* __restrict__ A2,
                               const float* __restrict__ norm,
                               const float* __restrict__ alpha,
                               const float* __restrict__ W,
                               const float* __restrict__ b,
                               float4* __restrict__ G1,     // in/out: staged g, final out
                               int n) {
    __shared__ float Wl[D][D + 1];
    __shared__ float pbuf[4][D];
    int tid = threadIdx.x;
    for (int k = tid; k < D * D; k += 256) Wl[k >> 5][k & 31] = W[k];
    __syncthreads();

    int wv = tid >> 6;   // wave in block
    int w = blockIdx.x * (blockDim.x >> 6) + wv;
    if (w >= n) return;
    int lane = tid & 63;
    int eo = lane >> 3;
    int q  = lane & 7;
    int s0 = row_start[w];
    int e1 = row_end[w];
    float4 acc = make_float4(0.f, 0.f, 0.f, 0.f);
    int j = s0 + eo;
    for (; j + 8 < e1; j += 16) {
        int sa = csr_src[j];
        int sb = csr_src[j + 8];
        float4 va = A2[(size_t)sa * 8 + q];
        float4 vb = A2[(size_t)sb * 8 + q];
        acc.x += va.x + vb.x; acc.y += va.y + vb.y;
        acc.z += va.z + vb.z; acc.w += va.w + vb.w;
    }
    if (j < e1) {
        int sa = csr_src[j];
        float4 va = A2[(size_t)sa * 8 + q];
        acc.x += va.x; acc.y += va.y; acc.z += va.z; acc.w += va.w;
    }
    acc = f4_shfl_xor_add(acc, 8);
    acc = f4_shfl_xor_add(acc, 16);
    acc = f4_shfl_xor_add(acc, 32);

    if (lane < 8) {
        float nv = norm[w];
        float a2 = alpha[2];
        float4 gv = G1[(size_t)w * 8 + q];
        float4 p = make_float4(fmaf(a2, acc.x * nv, gv.x), fmaf(a2, acc.y * nv, gv.y),
                               fmaf(a2, acc.z * nv, gv.z), fmaf(a2, acc.w * nv, gv.w));
        *(float4*)&pbuf[wv][q * 4] = p;
    }
    asm volatile("s_waitcnt lgkmcnt(0)" ::: "memory");

    // p @ W^T: lanes 0..31 -> outputs, halves split the k range, combine via xor 32
    int o  = lane & 31;
    int hi = lane >> 5;
    float acco = 0.f;
    #pragma unroll
    for (int k = 0; k < 16; ++k) {
        int kk = hi * 16 + k;
        acco = fmaf(pbuf[wv][kk], Wl[o][kk], acco);
    }
    acco += __shfl_xor(acco, 32);
    if (hi == 0) {
        float out = acco + 3.0f * b[o];
        ((float*)G1)[(size_t)w * D + o] = out;
    }
}

extern "C" void kernel_launch(void* const* d_in, const int* in_sizes, int n_in,
                              void* d_out, int out_size, void* d_ws, size_t ws_size,
                              hipStream_t stream) {
    const float* feat  = (const float*)d_in[0];
    const int*   src   = (const int*)  d_in[1];
    const int*   dst   = (const int*)  d_in[2];
    const float* W     = (const float*)d_in[3];
    const float* b     = (const float*)d_in[4];
    const float* alpha = (const float*)d_in[5];

    const int N  = in_sizes[0] / D;
    const int E  = in_sizes[1];
    const int BT = 256;
    const int nb = (N + SCAN_CHUNK - 1) / SCAN_CHUNK;   // must be <= 256
    const int e4blocks = ((E + 3) / 4 + BT - 1) / BT;

    // Path A: deg[N] pos[E] partial[256] row_start[N] row_end[N] csr_src[E] norm[N] A2[N*D]
    size_t needA = (size_t)(4 * N + 2 * E + 256 + N * D) * 4;
    // Path B: deg[N] partial[256] row_start[N] row_end[N] next[N] csr_src[E] norm[N] A2[N*D]
    size_t needB = (size_t)(5 * N + E + 256 + N * D) * 4;

    const int gblocks = (N + 3) / 4;      // 4 waves (rows) per 256-thread block
    float4* G1 = (float4*)d_out;

    if (ws_size >= needA && nb <= 256) {
        int*   deg       = (int*)d_ws;
        int*   pos       = deg + N;
        int*   partial   = pos + E;
        int*   row_start = partial + 256;
        int*   row_end   = row_start + N;
        int*   csr_src   = row_end + N;
        float* norm      = (float*)(csr_src + E);
        float* A2        = norm + N;

        hipMemsetAsync(deg, 0, (size_t)N * sizeof(int), stream);
        degpos_kernel<<<e4blocks, BT, 0, stream>>>(dst, deg, pos, E);
        scan1_kernel<<<nb, SCAN_T, 0, stream>>>(deg, partial, N);
        scan2_kernel<<<1, 256, 0, stream>>>(partial, nb);
        scan3_kernel<<<nb, SCAN_T, 0, stream>>>(deg, partial, row_start, row_end,
                                                (int*)nullptr, norm, N);
        fillA_kernel<<<e4blocks, BT, 0, stream>>>(src, dst, pos, row_start, csr_src, E);
        gather1_kernel<<<gblocks, BT, 0, stream>>>(row_start, row_end, csr_src,
                                                   (const float4*)feat, norm, alpha,
                                                   G1, (float4*)A2, N);
        gather2_kernel<<<gblocks, BT, 0, stream>>>(row_start, row_end, csr_src,
                                                   (const float4*)A2, norm, alpha,
                                                   W, b, G1, N);
    } else {
        (void)needB;
        int*   deg       = (int*)d_ws;
        int*   partial   = deg + N;
        int*   row_start = partial + 256;
        int*   row_end   = row_start + N;
        int*   next      = row_end + N;
        int*   csr_src   = next + N;
        float* norm      = (float*)(csr_src + E);
        float* A2        = norm + N;

        hipMemsetAsync(deg, 0, (size_t)N * sizeof(int), stream);
        deg_kernel<<<e4blocks, BT, 0, stream>>>(dst, deg, E);
        scan1_kernel<<<nb, SCAN_T, 0, stream>>>(deg, partial, N);
        scan2_kernel<<<1, 256, 0, stream>>>(partial, nb);
        scan3_kernel<<<nb, SCAN_T, 0, stream>>>(deg, partial, row_start, row_end, next, norm, N);
        fillB_kernel<<<(E + BT - 1) / BT, BT, 0, stream>>>(src, dst, next, csr_src, E);
        gather1_kernel<<<gblocks, BT, 0, stream>>>(row_start, row_end, csr_src,
                                                   (const float4*)feat, norm, alpha,
                                                   G1, (float4*)A2, N);
        gather2_kernel<<<gblocks, BT, 0, stream>>>(row_start, row_end, csr_src,
                                                   (const float4*)A2, norm, alpha,
                                                   W, b, G1, N);
    }
}

// Round 5
// 156.984 us; speedup vs baseline: 9.1201x; 1.3337x over previous
//
#include <hip/hip_runtime.h>

#define D 32
#define CHUNK 4096        // edges per build block
#define BWID 512          // nodes per bucket
#define BSH 9             // log2(BWID)
#define SCAN_T 256
#define SCAN_V 4
#define SCAN_CHUNK 1024

// ================= bucketed CSR build (no global atomics) =================

// ---- P1: per-block LDS histogram of dst buckets -> cnt[blk*NB + b] ----
__global__ void p1_count_kernel(const int* __restrict__ dst, int* __restrict__ cnt,
                                int E, int NB) {
    __shared__ int h[256];
    int blk = blockIdx.x, t = threadIdx.x;
    for (int i = t; i < 256; i += 256) h[i] = 0;
    __syncthreads();
    int base = blk * CHUNK;
    int end = min(base + CHUNK, E);
    int tbase = base + t * 16;
    #pragma unroll
    for (int k = 0; k < 4; ++k) {
        int a = tbase + k * 4;
        if (a + 3 < end) {
            int4 d = *(const int4*)(dst + a);
            atomicAdd(&h[d.x >> BSH], 1);
            atomicAdd(&h[d.y >> BSH], 1);
            atomicAdd(&h[d.z >> BSH], 1);
            atomicAdd(&h[d.w >> BSH], 1);
        } else {
            for (int e = a; e < end && e < a + 4; ++e) atomicAdd(&h[dst[e] >> BSH], 1);
        }
    }
    __syncthreads();
    for (int i = t; i < NB; i += 256) cnt[blk * NB + i] = h[i];
}

// ---- reduce per-bucket totals: btot[b] = sum_g cnt[g*NB+b] ----
__global__ void red_kernel(const int* __restrict__ cnt, int* __restrict__ btot,
                           int G1, int NB) {
    __shared__ int s[256];
    int b = blockIdx.x, t = threadIdx.x;
    int acc = 0;
    for (int g = t; g < G1; g += 256) acc += cnt[g * NB + b];
    s[t] = acc;
    __syncthreads();
    for (int off = 128; off > 0; off >>= 1) {
        if (t < off) s[t] += s[t + off];
        __syncthreads();
    }
    if (t == 0) btot[b] = s[0];
}

// ---- exclusive scan of bucket totals -> bbase[0..NB], bbase[NB]=E ----
__global__ void scanb_kernel(const int* __restrict__ btot, int* __restrict__ bbase, int NB) {
    __shared__ int s[256];
    int t = threadIdx.x;
    int v = (t < NB) ? btot[t] : 0;
    s[t] = v;
    __syncthreads();
    for (int off = 1; off < 256; off <<= 1) {
        int x = (t >= off) ? s[t - off] : 0;
        __syncthreads();
        s[t] += x;
        __syncthreads();
    }
    if (t < NB) bbase[t] = s[t] - v;
    if (t == NB - 1) bbase[NB] = s[t];
}

// ---- per-bucket exclusive scan over blocks: off[g*NB+b] = bbase[b] + prefix ----
__global__ void off_kernel(const int* __restrict__ cnt, const int* __restrict__ bbase,
                           int* __restrict__ off, int G1, int NB) {
    __shared__ int st[256];
    int b = blockIdx.x, t = threadIdx.x;
    int g0 = 2 * t, g1 = 2 * t + 1;
    int c0 = (g0 < G1) ? cnt[g0 * NB + b] : 0;
    int c1 = (g1 < G1) ? cnt[g1 * NB + b] : 0;
    int pair = c0 + c1;
    st[t] = pair;
    __syncthreads();
    for (int o = 1; o < 256; o <<= 1) {
        int x = (t >= o) ? st[t - o] : 0;
        __syncthreads();
        st[t] += x;
        __syncthreads();
    }
    int ex = bbase[b] + st[t] - pair;
    if (g0 < G1) off[g0 * NB + b] = ex;
    if (g1 < G1) off[g1 * NB + b] = ex + c0;
}

// ---- P3: bucket-scatter packed (dstlocal<<23 | src) using LDS cursors ----
__global__ void p3_scatter_kernel(const int* __restrict__ src, const int* __restrict__ dst,
                                  const int* __restrict__ off, unsigned* __restrict__ ebuf,
                                  int E, int NB) {
    __shared__ int cur[256];
    int blk = blockIdx.x, t = threadIdx.x;
    for (int i = t; i < NB; i += 256) cur[i] = off[blk * NB + i];
    __syncthreads();
    int base = blk * CHUNK;
    int end = min(base + CHUNK, E);
    int tbase = base + t * 16;
    #pragma unroll
    for (int k = 0; k < 4; ++k) {
        int a = tbase + k * 4;
        if (a + 3 < end) {
            int4 d = *(const int4*)(dst + a);
            int4 s = *(const int4*)(src + a);
            int p0 = atomicAdd(&cur[d.x >> BSH], 1);
            int p1 = atomicAdd(&cur[d.y >> BSH], 1);
            int p2 = atomicAdd(&cur[d.z >> BSH], 1);
            int p3 = atomicAdd(&cur[d.w >> BSH], 1);
            ebuf[p0] = ((unsigned)(d.x & (BWID - 1)) << 23) | (unsigned)s.x;
            ebuf[p1] = ((unsigned)(d.y & (BWID - 1)) << 23) | (unsigned)s.y;
            ebuf[p2] = ((unsigned)(d.z & (BWID - 1)) << 23) | (unsigned)s.z;
            ebuf[p3] = ((unsigned)(d.w & (BWID - 1)) << 23) | (unsigned)s.w;
        } else {
            for (int e = a; e < end && e < a + 4; ++e) {
                int dv = dst[e];
                int p = atomicAdd(&cur[dv >> BSH], 1);
                ebuf[p] = ((unsigned)(dv & (BWID - 1)) << 23) | (unsigned)src[e];
            }
        }
    }
}

// ---- P4: per-bucket finalize -> row_start/row_end/norm + csr_src ----
__global__ void p4_kernel(const unsigned* __restrict__ ebuf, const int* __restrict__ bbase,
                          int* __restrict__ row_start, int* __restrict__ row_end,
                          float* __restrict__ norm, int* __restrict__ csr_src, int N) {
    __shared__ int deg2[BWID];
    __shared__ int rs[BWID];
    __shared__ int st[256];
    int b = blockIdx.x, t = threadIdx.x;
    int node0 = b << BSH;
    int nn = min(BWID, N - node0);
    int e0 = bbase[b], e1 = bbase[b + 1];
    deg2[t] = 0; deg2[t + 256] = 0;
    __syncthreads();
    for (int j = e0 + t; j < e1; j += 256)
        atomicAdd(&deg2[ebuf[j] >> 23], 1);
    __syncthreads();
    int d0 = deg2[2 * t], d1 = deg2[2 * t + 1];
    int pair = d0 + d1;
    st[t] = pair;
    __syncthreads();
    for (int off = 1; off < 256; off <<= 1) {
        int v = (t >= off) ? st[t - off] : 0;
        __syncthreads();
        st[t] += v;
        __syncthreads();
    }
    int ex = st[t] - pair;
    rs[2 * t] = ex;
    rs[2 * t + 1] = ex + d0;
    __syncthreads();
    #pragma unroll
    for (int k = 0; k < 2; ++k) {
        int i = t + k * 256;
        if (i < nn) {
            int dg = deg2[i];
            int r = e0 + rs[i];
            row_start[node0 + i] = r;
            row_end[node0 + i]   = r + dg;
            norm[node0 + i] = rsqrtf(fmaxf((float)dg, 1.0f));
        }
    }
    __syncthreads();
    for (int j = e0 + t; j < e1; j += 256) {
        unsigned v = ebuf[j];
        int dl = v >> 23;
        int p = atomicAdd(&rs[dl], 1);
        csr_src[e0 + p] = (int)(v & 0x7FFFFF);
    }
}

// ================= fallback build (R3 path, global atomics) =================
__global__ void degpos_kernel(const int* __restrict__ dst, int* __restrict__ deg,
                              int* __restrict__ pos, int E) {
    int t = blockIdx.x * blockDim.x + threadIdx.x;
    int base = t * 4;
    if (base + 3 < E) {
        int4 d = *(const int4*)(dst + base);
        int4 p;
        p.x = atomicAdd(&deg[d.x], 1);
        p.y = atomicAdd(&deg[d.y], 1);
        p.z = atomicAdd(&deg[d.z], 1);
        p.w = atomicAdd(&deg[d.w], 1);
        *(int4*)(pos + base) = p;
    } else if (base < E) {
        for (int e = base; e < E; ++e) pos[e] = atomicAdd(&deg[dst[e]], 1);
    }
}

__global__ void scan1_kernel(const int* __restrict__ deg, int* __restrict__ partial, int n) {
    __shared__ int sdata[SCAN_T];
    int base = blockIdx.x * SCAN_CHUNK + threadIdx.x * SCAN_V;
    int s = 0;
    #pragma unroll
    for (int k = 0; k < SCAN_V; ++k) { int i = base + k; if (i < n) s += deg[i]; }
    sdata[threadIdx.x] = s;
    __syncthreads();
    for (int off = SCAN_T / 2; off > 0; off >>= 1) {
        if (threadIdx.x < off) sdata[threadIdx.x] += sdata[threadIdx.x + off];
        __syncthreads();
    }
    if (threadIdx.x == 0) partial[blockIdx.x] = sdata[0];
}

__global__ void scan2_kernel(int* __restrict__ partial, int nb) {
    __shared__ int sdata[256];
    int v = (threadIdx.x < nb) ? partial[threadIdx.x] : 0;
    sdata[threadIdx.x] = v;
    __syncthreads();
    for (int off = 1; off < 256; off <<= 1) {
        int t = (threadIdx.x >= off) ? sdata[threadIdx.x - off] : 0;
        __syncthreads();
        sdata[threadIdx.x] += t;
        __syncthreads();
    }
    if (threadIdx.x < nb) partial[threadIdx.x] = sdata[threadIdx.x] - v;
}

__global__ void scan3_kernel(const int* __restrict__ deg, const int* __restrict__ partial,
                             int* __restrict__ row_start, int* __restrict__ row_end,
                             float* __restrict__ norm, int n) {
    __shared__ int sdata[SCAN_T];
    int base = blockIdx.x * SCAN_CHUNK + threadIdx.x * SCAN_V;
    int v[SCAN_V];
    int s = 0;
    #pragma unroll
    for (int k = 0; k < SCAN_V; ++k) { int i = base + k; v[k] = (i < n) ? deg[i] : 0; s += v[k]; }
    int self = s;
    sdata[threadIdx.x] = s;
    __syncthreads();
    for (int off = 1; off < SCAN_T; off <<= 1) {
        int t = (threadIdx.x >= off) ? sdata[threadIdx.x - off] : 0;
        __syncthreads();
        sdata[threadIdx.x] += t;
        __syncthreads();
    }
    int run = partial[blockIdx.x] + sdata[threadIdx.x] - self;
    #pragma unroll
    for (int k = 0; k < SCAN_V; ++k) {
        int i = base + k;
        if (i < n) {
            row_start[i] = run;
            row_end[i]   = run + v[k];
            norm[i] = rsqrtf(fmaxf((float)v[k], 1.0f));
            run += v[k];
        }
    }
}

__global__ void fillA_kernel(const int* __restrict__ src, const int* __restrict__ dst,
                             const int* __restrict__ pos, const int* __restrict__ row_start,
                             int* __restrict__ csr_src, int E) {
    int t = blockIdx.x * blockDim.x + threadIdx.x;
    int base = t * 4;
    if (base + 3 < E) {
        int4 d = *(const int4*)(dst + base);
        int4 p = *(const int4*)(pos + base);
        int4 s = *(const int4*)(src + base);
        csr_src[row_start[d.x] + p.x] = s.x;
        csr_src[row_start[d.y] + p.y] = s.y;
        csr_src[row_start[d.z] + p.z] = s.z;
        csr_src[row_start[d.w] + p.w] = s.w;
    } else if (base < E) {
        for (int e = base; e < E; ++e)
            csr_src[row_start[dst[e]] + pos[e]] = src[e];
    }
}

// ================= gathers (unchanged from R3) =================
__device__ __forceinline__ float4 f4_shfl_xor_add(float4 a, int mask) {
    a.x += __shfl_xor(a.x, mask);
    a.y += __shfl_xor(a.y, mask);
    a.z += __shfl_xor(a.z, mask);
    a.w += __shfl_xor(a.w, mask);
    return a;
}

__global__ void gather1_kernel(const int* __restrict__ row_start,
                               const int* __restrict__ row_end,
                               const int* __restrict__ csr_src,
                               const float4* __restrict__ feat4,
                               const float* __restrict__ norm,
                               const float* __restrict__ alpha,
                               float4* __restrict__ G1,
                               float4* __restrict__ A2, int n) {
    int w = blockIdx.x * (blockDim.x >> 6) + (threadIdx.x >> 6);
    if (w >= n) return;
    int lane = threadIdx.x & 63;
    int eo = lane >> 3;
    int q  = lane & 7;
    int s0 = row_start[w];
    int e1 = row_end[w];
    float4 acc = make_float4(0.f, 0.f, 0.f, 0.f);
    int j = s0 + eo;
    for (; j + 8 < e1; j += 16) {
        int sa = csr_src[j];
        int sb = csr_src[j + 8];
        float na = norm[sa];
        float nb = norm[sb];
        float4 va = feat4[(size_t)sa * 8 + q];
        float4 vb = feat4[(size_t)sb * 8 + q];
        acc.x += va.x * na + vb.x * nb;
        acc.y += va.y * na + vb.y * nb;
        acc.z += va.z * na + vb.z * nb;
        acc.w += va.w * na + vb.w * nb;
    }
    if (j < e1) {
        int sa = csr_src[j];
        float na = norm[sa];
        float4 va = feat4[(size_t)sa * 8 + q];
        acc.x += va.x * na; acc.y += va.y * na;
        acc.z += va.z * na; acc.w += va.w * na;
    }
    acc = f4_shfl_xor_add(acc, 8);
    acc = f4_shfl_xor_add(acc, 16);
    acc = f4_shfl_xor_add(acc, 32);
    if (lane < 8) {
        float nv = norm[w];
        float a0 = alpha[0], a1 = alpha[1];
        float4 f = feat4[(size_t)w * 8 + q];
        float4 h1 = make_float4(acc.x * nv, acc.y * nv, acc.z * nv, acc.w * nv);
        size_t o = (size_t)w * 8 + q;
        G1[o] = make_float4(fmaf(a1, h1.x, a0 * f.x), fmaf(a1, h1.y, a0 * f.y),
                            fmaf(a1, h1.z, a0 * f.z), fmaf(a1, h1.w, a0 * f.w));
        A2[o] = make_float4(h1.x * nv, h1.y * nv, h1.z * nv, h1.w * nv);
    }
}

__global__ void gather2_kernel(const int* __restrict__ row_start,
                               const int* __restrict__ row_end,
                               const int* __restrict__ csr_src,
                               const float4* __restrict__ A2,
                               const float* __restrict__ norm,
                               const float* __restrict__ alpha,
                               const float* __restrict__ W,
                               const float* __restrict__ b,
                               float4* __restrict__ G1, int n) {
    __shared__ float Wl[D][D + 1];
    __shared__ float pbuf[4][D];
    int tid = threadIdx.x;
    for (int k = tid; k < D * D; k += 256) Wl[k >> 5][k & 31] = W[k];
    __syncthreads();

    int wv = tid >> 6;
    int w = blockIdx.x * (blockDim.x >> 6) + wv;
    if (w >= n) return;
    int lane = tid & 63;
    int eo = lane >> 3;
    int q  = lane & 7;
    int s0 = row_start[w];
    int e1 = row_end[w];
    float4 acc = make_float4(0.f, 0.f, 0.f, 0.f);
    int j = s0 + eo;
    for (; j + 8 < e1; j += 16) {
        int sa = csr_src[j];
        int sb = csr_src[j + 8];
        float4 va = A2[(size_t)sa * 8 + q];
        float4 vb = A2[(size_t)sb * 8 + q];
        acc.x += va.x + vb.x; acc.y += va.y + vb.y;
        acc.z += va.z + vb.z; acc.w += va.w + vb.w;
    }
    if (j < e1) {
        int sa = csr_src[j];
        float4 va = A2[(size_t)sa * 8 + q];
        acc.x += va.x; acc.y += va.y; acc.z += va.z; acc.w += va.w;
    }
    acc = f4_shfl_xor_add(acc, 8);
    acc = f4_shfl_xor_add(acc, 16);
    acc = f4_shfl_xor_add(acc, 32);

    if (lane < 8) {
        float nv = norm[w];
        float a2 = alpha[2];
        float4 gv = G1[(size_t)w * 8 + q];
        float4 p = make_float4(fmaf(a2, acc.x * nv, gv.x), fmaf(a2, acc.y * nv, gv.y),
                               fmaf(a2, acc.z * nv, gv.z), fmaf(a2, acc.w * nv, gv.w));
        *(float4*)&pbuf[wv][q * 4] = p;
    }
    asm volatile("s_waitcnt lgkmcnt(0)" ::: "memory");

    int o  = lane & 31;
    int hi = lane >> 5;
    float acco = 0.f;
    #pragma unroll
    for (int k = 0; k < 16; ++k) {
        int kk = hi * 16 + k;
        acco = fmaf(pbuf[wv][kk], Wl[o][kk], acco);
    }
    acco += __shfl_xor(acco, 32);
    if (hi == 0) {
        float out = acco + 3.0f * b[o];
        ((float*)G1)[(size_t)w * D + o] = out;
    }
}

extern "C" void kernel_launch(void* const* d_in, const int* in_sizes, int n_in,
                              void* d_out, int out_size, void* d_ws, size_t ws_size,
                              hipStream_t stream) {
    const float* feat  = (const float*)d_in[0];
    const int*   src   = (const int*)  d_in[1];
    const int*   dst   = (const int*)  d_in[2];
    const float* W     = (const float*)d_in[3];
    const float* b     = (const float*)d_in[4];
    const float* alpha = (const float*)d_in[5];

    const int N  = in_sizes[0] / D;
    const int E  = in_sizes[1];
    const int BT = 256;
    const int NB = (N + BWID - 1) >> BSH;           // buckets
    const int G1 = (E + CHUNK - 1) / CHUNK;         // build blocks
    const int gblocks = (N + 3) / 4;                // 4 rows / 256-thread block
    float4* G = (float4*)d_out;

    // bucketed path: cnt[G1*NB] off[G1*NB] btot[NB] bbase[NB+1] ebuf[E] csr[E] rs[N] re[N] norm[N] A2[N*D]
    size_t needA = ((size_t)2 * G1 * NB + 2 * NB + 1 + 2 * (size_t)E + 3 * (size_t)N
                    + (size_t)N * D) * 4;

    if (ws_size >= needA && NB <= 256 && G1 <= 512 && N < (1 << 23)) {
        int*      cnt       = (int*)d_ws;
        int*      off       = cnt + (size_t)G1 * NB;
        int*      btot      = off + (size_t)G1 * NB;
        int*      bbase     = btot + NB;
        unsigned* ebuf      = (unsigned*)(bbase + NB + 1);
        int*      csr_src   = (int*)(ebuf + E);
        int*      row_start = csr_src + E;
        int*      row_end   = row_start + N;
        float*    norm      = (float*)(row_end + N);
        float*    A2        = norm + N;

        p1_count_kernel<<<G1, BT, 0, stream>>>(dst, cnt, E, NB);
        red_kernel<<<NB, BT, 0, stream>>>(cnt, btot, G1, NB);
        scanb_kernel<<<1, BT, 0, stream>>>(btot, bbase, NB);
        off_kernel<<<NB, BT, 0, stream>>>(cnt, bbase, off, G1, NB);
        p3_scatter_kernel<<<G1, BT, 0, stream>>>(src, dst, off, ebuf, E, NB);
        p4_kernel<<<NB, BT, 0, stream>>>(ebuf, bbase, row_start, row_end, norm, csr_src, N);
        gather1_kernel<<<gblocks, BT, 0, stream>>>(row_start, row_end, csr_src,
                                                   (const float4*)feat, norm, alpha,
                                                   G, (float4*)A2, N);
        gather2_kernel<<<gblocks, BT, 0, stream>>>(row_start, row_end, csr_src,
                                                   (const float4*)A2, norm, alpha,
                                                   W, b, G, N);
    } else {
        // fallback: R3 global-atomic build
        const int nb = (N + SCAN_CHUNK - 1) / SCAN_CHUNK;
        const int e4blocks = ((E + 3) / 4 + BT - 1) / BT;
        int*   deg       = (int*)d_ws;
        int*   pos       = deg + N;
        int*   partial   = pos + E;
        int*   row_start = partial + 256;
        int*   row_end   = row_start + N;
        int*   csr_src   = row_end + N;
        float* norm      = (float*)(csr_src + E);
        float* A2        = norm + N;

        hipMemsetAsync(deg, 0, (size_t)N * sizeof(int), stream);
        degpos_kernel<<<e4blocks, BT, 0, stream>>>(dst, deg, pos, E);
        scan1_kernel<<<nb, SCAN_T, 0, stream>>>(deg, partial, N);
        scan2_kernel<<<1, 256, 0, stream>>>(partial, nb);
        scan3_kernel<<<nb, SCAN_T, 0, stream>>>(deg, partial, row_start, row_end, norm, N);
        fillA_kernel<<<e4blocks, BT, 0, stream>>>(src, dst, pos, row_start, csr_src, E);
        gather1_kernel<<<gblocks, BT, 0, stream>>>(row_start, row_end, csr_src,
                                                   (const float4*)feat, norm, alpha,
                                                   G, (float4*)A2, N);
        gather2_kernel<<<gblocks, BT, 0, stream>>>(row_start, row_end, csr_src,
                                                   (const float4*)A2, norm, alpha,
                                                   W, b, G, N);
    }
}